// Round 4
// baseline (547.609 us; speedup 1.0000x reference)
//
#include <hip/hip_runtime.h>
#include <hip/hip_bf16.h>

// DQNNetwork: M=65536, K=768 features, N=512 hidden, 3 actions. All I/O fp32.
//   h = relu(X @ Wh^T + bh)
//   out[i,a] = relu( sum_g h[i,g]*W'[a,g] + c[a] )
//     W'[a,g] = Wf[a,g] - Wf[a,512+g]/(M-1)
//     c[a]    = bf[a] + (sum_g colsum[g]*Wf[a,512+g])/(M-1)
// Head is fused into the GEMM epilogue via per-row atomic partial dots (pdot);
// H is never materialized.

#define M_DIM 65536
#define K_DIM 768
#define N_DIM 512
#define INV_NM1 (1.0f / 65535.0f)

typedef __attribute__((ext_vector_type(8))) short shortx8;   // 8 bf16 (4 VGPRs)
typedef __attribute__((ext_vector_type(4))) float floatx4;   // MFMA C/D

__device__ __forceinline__ unsigned short f2b(float f) {
    unsigned u = __float_as_uint(f);
    unsigned r = (u + 0x7fffu + ((u >> 16) & 1u)) >> 16;   // RNE
    return (unsigned short)r;
}

#if defined(__has_builtin)
#  if __has_builtin(__builtin_amdgcn_cvt_pk_bf16_f32)
#    define HAVE_CVT_PK_BF16 1
#  endif
#endif

// pack two fp32 -> two bf16 (RNE) in one uint. HW v_cvt_pk_bf16_f32 on gfx950.
__device__ __forceinline__ unsigned pack2bf(float x, float y) {
#ifdef HAVE_CVT_PK_BF16
    typedef __attribute__((ext_vector_type(2))) __bf16 bf16x2_t;
    bf16x2_t t = __builtin_amdgcn_cvt_pk_bf16_f32(x, y);
    return __builtin_bit_cast(unsigned, t);
#else
    return (unsigned)f2b(x) | ((unsigned)f2b(y) << 16);
#endif
}

// ---------------------------------------------------------------------------
// Fused GEMM + head-partial.
// 128x128 C-tile, 256 thr = 4 waves (2x2 of 64x64), BK=64, 16x16x32 bf16 MFMA.
// LDS: row-major [128][64] bf16, 16B chunk j of row r stored at j^(r&7)
// (b128 frag reads then alias only 2-way per bank = free; writes stay clean).
// Block swizzle: the 4 n-blocks of an m-tile get ids == (mod 8) -> same XCD,
// so X tiles are fetched from HBM once per tile.
// ---------------------------------------------------------------------------
__global__ __launch_bounds__(256, 4) void gemm_fused_kernel(
    const float* __restrict__ X,     // [M,K] fp32
    const float* __restrict__ Wh,    // [N,K] fp32 (B^T layout)
    const float* __restrict__ bh,    // [N]
    const float* __restrict__ Wf,    // [3,1024]
    float* __restrict__ colsum,      // [N] fp32, pre-zeroed
    float* __restrict__ pdot)        // [M,3] fp32, pre-zeroed
{
    __shared__ unsigned short As[128 * 64];  // 16 KB
    __shared__ unsigned short Bs[128 * 64];  // 16 KB

    const int tid  = threadIdx.x;
    const int wave = tid >> 6;
    const int lane = tid & 63;
    const int l16  = lane & 15;
    const int quad = lane >> 4;
    const int wm   = wave >> 1;
    const int wn   = wave & 1;

    // XCD-aware swizzle: b = g*32 + slot*8 + xcd ; m-index = g*8+xcd, n = slot.
    const int b  = blockIdx.x;
    const int g  = b >> 5;
    const int r  = b & 31;
    const int m0 = (g * 8 + (r & 7)) * 128;
    const int n0 = (r >> 3) * 128;

    floatx4 acc[4][4];
    #pragma unroll
    for (int i = 0; i < 4; i++)
        #pragma unroll
        for (int j = 0; j < 4; j++) {
            floatx4 z = {0.f, 0.f, 0.f, 0.f};
            acc[i][j] = z;
        }

    const int swr = l16 & 7;   // read-side swizzle key (row&7 == l16&7)

    for (int k0 = 0; k0 < K_DIM; k0 += 64) {
        // Stage 128x64 fp32 -> bf16. 2048 float4-chunks per tile, 8 passes.
        #pragma unroll
        for (int p = 0; p < 8; p++) {
            const int c   = p * 256 + tid;     // 0..2047
            const int row = c >> 4;            // 0..127
            const int q   = c & 15;
            const int f4  = q << 2;            // elem in row: 0..60
            const int jch = q >> 1;            // 16B chunk 0..7
            const int off = row * 64 + ((jch ^ (row & 7)) << 3) + ((q & 1) << 2);
            const float4 av = *(const float4*)(X  + (size_t)(m0 + row) * K_DIM + k0 + f4);
            const float4 bv = *(const float4*)(Wh + (size_t)(n0 + row) * K_DIM + k0 + f4);
            uint2 a2, b2;
            a2.x = pack2bf(av.x, av.y); a2.y = pack2bf(av.z, av.w);
            b2.x = pack2bf(bv.x, bv.y); b2.y = pack2bf(bv.z, bv.w);
            *(uint2*)(As + off) = a2;
            *(uint2*)(Bs + off) = b2;
        }
        __syncthreads();

        #pragma unroll
        for (int kk = 0; kk < 64; kk += 32) {
            shortx8 afrag[4], bfrag[4];
            const int jq = (kk >> 3) + quad;             // chunk index 0..7
            const int co = ((jq ^ swr) << 3);            // swizzled chunk offset
            #pragma unroll
            for (int mt = 0; mt < 4; mt++)
                afrag[mt] = *(const shortx8*)(As + (wm * 64 + mt * 16 + l16) * 64 + co);
            #pragma unroll
            for (int nt = 0; nt < 4; nt++)
                bfrag[nt] = *(const shortx8*)(Bs + (wn * 64 + nt * 16 + l16) * 64 + co);
            #pragma unroll
            for (int mt = 0; mt < 4; mt++)
                #pragma unroll
                for (int nt = 0; nt < 4; nt++)
                    acc[mt][nt] = __builtin_amdgcn_mfma_f32_16x16x32_bf16(
                        afrag[mt], bfrag[nt], acc[mt][nt], 0, 0, 0);
        }
        __syncthreads();
    }

    // ---- Epilogue. C/D layout: col = lane&15, row = quad*4 + reg. ----
    float bhv[4], wpr0[4], wpr1[4], wpr2[4];
    #pragma unroll
    for (int nt = 0; nt < 4; nt++) {
        const int col = n0 + wn * 64 + nt * 16 + l16;
        bhv[nt]  = bh[col];
        wpr0[nt] = Wf[col]        - Wf[512 + col]  * INV_NM1;
        wpr1[nt] = Wf[1024 + col] - Wf[1536 + col] * INV_NM1;
        wpr2[nt] = Wf[2048 + col] - Wf[2560 + col] * INV_NM1;
    }

    float cscol[4] = {0.f, 0.f, 0.f, 0.f};
    #pragma unroll
    for (int mt = 0; mt < 4; mt++) {
        #pragma unroll
        for (int rg = 0; rg < 4; rg++) {
            float p0 = 0.f, p1 = 0.f, p2 = 0.f;
            #pragma unroll
            for (int nt = 0; nt < 4; nt++) {
                float v = acc[mt][nt][rg] + bhv[nt];
                v = v > 0.f ? v : 0.f;
                cscol[nt] += v;
                p0 += v * wpr0[nt];
                p1 += v * wpr1[nt];
                p2 += v * wpr2[nt];
            }
            // reduce the 16 lanes of this quad (same row, cols l16-spread)
            #pragma unroll
            for (int off = 1; off < 16; off <<= 1) {
                p0 += __shfl_xor(p0, off, 64);
                p1 += __shfl_xor(p1, off, 64);
                p2 += __shfl_xor(p2, off, 64);
            }
            if (l16 == 0) {
                const int row = m0 + wm * 64 + mt * 16 + quad * 4 + rg;
                atomicAdd(&pdot[row * 3 + 0], p0);
                atomicAdd(&pdot[row * 3 + 1], p1);
                atomicAdd(&pdot[row * 3 + 2], p2);
            }
        }
    }
    // colsum: same column lives in lanes {l16, +16, +32, +48}
    #pragma unroll
    for (int nt = 0; nt < 4; nt++) {
        float v = cscol[nt];
        v += __shfl_xor(v, 16, 64);
        v += __shfl_xor(v, 32, 64);
        if (lane < 16)
            atomicAdd(&colsum[n0 + wn * 64 + nt * 16 + l16], v);
    }
}

// ---------------------------------------------------------------------------
// finalize: out[i,a] = relu(pdot[i,a] + c[a]); wave 0 computes c[a].
// grid 768 x 256 covers 196608 elements exactly.
// ---------------------------------------------------------------------------
__global__ __launch_bounds__(256) void finalize_kernel(
    const float* __restrict__ pdot,     // [M,3]
    const float* __restrict__ Wf,       // [3,1024]
    const float* __restrict__ bfb,      // [3]
    const float* __restrict__ colsum,   // [512]
    float* __restrict__ out)            // [M*3]
{
    __shared__ float csh[3];
    const int tid = threadIdx.x;
    if (tid < 64) {
        const int g0 = tid * 8;
        float cp[3] = {0.f, 0.f, 0.f};
        #pragma unroll
        for (int a = 0; a < 3; a++)
            #pragma unroll
            for (int j = 0; j < 8; j++)
                cp[a] += colsum[g0 + j] * Wf[a * 1024 + 512 + g0 + j];
        #pragma unroll
        for (int a = 0; a < 3; a++)
            #pragma unroll
            for (int off = 1; off < 64; off <<= 1)
                cp[a] += __shfl_xor(cp[a], off, 64);
        if (tid == 0) {
            #pragma unroll
            for (int a = 0; a < 3; a++)
                csh[a] = cp[a] * INV_NM1 + bfb[a];
        }
    }
    __syncthreads();
    const int idx = blockIdx.x * 256 + tid;
    const float v = pdot[idx] + csh[idx % 3];
    out[idx] = v > 0.f ? v : 0.f;
}

extern "C" void kernel_launch(void* const* d_in, const int* in_sizes, int n_in,
                              void* d_out, int out_size, void* d_ws, size_t ws_size,
                              hipStream_t stream) {
    const float* X   = (const float*)d_in[0];
    const float* Wh  = (const float*)d_in[1];
    const float* bh  = (const float*)d_in[2];
    const float* Wf  = (const float*)d_in[3];
    const float* bfb = (const float*)d_in[4];
    for (int i = 0; i < n_in; i++) {
        const float* p = (const float*)d_in[i];
        switch (in_sizes[i]) {
            case M_DIM * K_DIM: X   = p; break;
            case N_DIM * K_DIM: Wh  = p; break;
            case N_DIM:         bh  = p; break;
            case 3 * 2 * N_DIM: Wf  = p; break;
            case 3:             bfb = p; break;
            default: break;
        }
    }
    float* out    = (float*)d_out;
    float* colsum = (float*)d_ws;                          // 512 fp32
    float* pdot   = (float*)((char*)d_ws + 2048);          // 196608 fp32

    hipMemsetAsync(d_ws, 0, 2048 + (size_t)M_DIM * 3 * sizeof(float), stream);

    gemm_fused_kernel<<<2048, 256, 0, stream>>>(X, Wh, bh, Wf, colsum, pdot);
    finalize_kernel<<<M_DIM * 3 / 256, 256, 0, stream>>>(pdot, Wf, bfb, colsum, out);
}

// Round 5
// 497.723 us; speedup vs baseline: 1.1002x; 1.1002x over previous
//
#include <hip/hip_runtime.h>
#include <hip/hip_bf16.h>

// DQNNetwork: M=65536, K=768, N=512 hidden, 3 actions. All I/O fp32.
//   h = relu(X @ Wh^T + bh)
//   d1[i,a] = dot(h[i], Wf[a,   0:512])
//   d2[i,a] = dot(h[i], Wf[a, 512:1024])
//   out[i,a] = relu( d1 - d2/(M-1) + bf[a] + (sum_i d2[i,a])/(M-1) )
// Epilogue computes p = d1 - d2*INV via combined weights wpr, plus per-block
// partial of sum_i d2 (3 atomicAdds/block). No H materialization, no colsum.

#define M_DIM 65536
#define K_DIM 768
#define N_DIM 512
#define INV_NM1 (1.0f / 65535.0f)
#define OUT_ELEMS (M_DIM * 3)

typedef __attribute__((ext_vector_type(8))) short shortx8;   // 8 bf16 (4 VGPRs)
typedef __attribute__((ext_vector_type(4))) float floatx4;   // MFMA C/D

__device__ __forceinline__ unsigned short f2b(float f) {
    unsigned u = __float_as_uint(f);
    unsigned r = (u + 0x7fffu + ((u >> 16) & 1u)) >> 16;   // RNE
    return (unsigned short)r;
}

#if defined(__has_builtin)
#  if __has_builtin(__builtin_amdgcn_cvt_pk_bf16_f32)
#    define HAVE_CVT_PK_BF16 1
#  endif
#endif

__device__ __forceinline__ unsigned pack2bf(float x, float y) {
#ifdef HAVE_CVT_PK_BF16
    typedef __attribute__((ext_vector_type(2))) __bf16 bf16x2_t;
    bf16x2_t t = __builtin_amdgcn_cvt_pk_bf16_f32(x, y);
    return __builtin_bit_cast(unsigned, t);
#else
    return (unsigned)f2b(x) | ((unsigned)f2b(y) << 16);
#endif
}

// ---------------------------------------------------------------------------
// Fused GEMM + head.
// 128x128 C-tile, 256 thr = 4 waves (2x2 of 64x64), BK=64, 16x16x32 bf16 MFMA.
// LDS: [128][64] bf16, 16B chunk j of row r at j^(r&7) (conflict-free, R4-
// verified: SQ_LDS_BANK_CONFLICT=0). Block swizzle: 4 n-blocks of one m-tile
// get ids congruent mod 8 -> same XCD -> X fetched once (R4: FETCH 399->144MB).
// NO min-wave bound: forcing 4 waves/EU spilled acc[4][4] in R4 (64 VGPRs,
// WRITE 2x, all pipes idle).
// ---------------------------------------------------------------------------
__global__ __launch_bounds__(256) void gemm_fused_kernel(
    const float* __restrict__ X,      // [M,K] fp32
    const float* __restrict__ Wh,     // [N,K] fp32 (B^T layout)
    const float* __restrict__ bh,     // [N]
    const float* __restrict__ Wf,     // [3,1024]
    float* __restrict__ gsum,         // [3] fp32, pre-zeroed (sum_i d2[i,a])
    float* __restrict__ pslice)       // [8][M*3] fp32, every elem written once
{
    __shared__ unsigned short As[128 * 64];  // 16 KB
    __shared__ unsigned short Bs[128 * 64];  // 16 KB
    __shared__ float gsh[4][3];

    const int tid  = threadIdx.x;
    const int wave = tid >> 6;
    const int lane = tid & 63;
    const int l16  = lane & 15;
    const int quad = lane >> 4;
    const int wm   = wave >> 1;
    const int wn   = wave & 1;

    // XCD-aware swizzle: b = g*32 + slot*8 + xcd ; m-index = g*8+xcd, n = slot.
    const int b  = blockIdx.x;
    const int g  = b >> 5;
    const int r  = b & 31;
    const int m0 = (g * 8 + (r & 7)) * 128;
    const int n0 = (r >> 3) * 128;

    floatx4 acc[4][4];
    #pragma unroll
    for (int i = 0; i < 4; i++)
        #pragma unroll
        for (int j = 0; j < 4; j++) {
            floatx4 z = {0.f, 0.f, 0.f, 0.f};
            acc[i][j] = z;
        }

    const int swr = l16 & 7;   // read-side swizzle key (row&7 == l16&7)

    for (int k0 = 0; k0 < K_DIM; k0 += 64) {
        // Stage 128x64 fp32 -> bf16. 2048 float4-chunks per tile, 8 passes.
        #pragma unroll
        for (int p = 0; p < 8; p++) {
            const int c   = p * 256 + tid;     // 0..2047
            const int row = c >> 4;            // 0..127
            const int q   = c & 15;
            const int f4  = q << 2;            // elem in row: 0..60
            const int jch = q >> 1;            // 16B chunk 0..7
            const int off = row * 64 + ((jch ^ (row & 7)) << 3) + ((q & 1) << 2);
            const float4 av = *(const float4*)(X  + (size_t)(m0 + row) * K_DIM + k0 + f4);
            const float4 bv = *(const float4*)(Wh + (size_t)(n0 + row) * K_DIM + k0 + f4);
            uint2 a2, b2;
            a2.x = pack2bf(av.x, av.y); a2.y = pack2bf(av.z, av.w);
            b2.x = pack2bf(bv.x, bv.y); b2.y = pack2bf(bv.z, bv.w);
            *(uint2*)(As + off) = a2;
            *(uint2*)(Bs + off) = b2;
        }
        __syncthreads();

        #pragma unroll
        for (int kk = 0; kk < 64; kk += 32) {
            shortx8 afrag[4], bfrag[4];
            const int jq = (kk >> 3) + quad;             // chunk index
            const int co = ((jq ^ swr) << 3);            // swizzled chunk offset
            #pragma unroll
            for (int mt = 0; mt < 4; mt++)
                afrag[mt] = *(const shortx8*)(As + (wm * 64 + mt * 16 + l16) * 64 + co);
            #pragma unroll
            for (int nt = 0; nt < 4; nt++)
                bfrag[nt] = *(const shortx8*)(Bs + (wn * 64 + nt * 16 + l16) * 64 + co);
            #pragma unroll
            for (int mt = 0; mt < 4; mt++)
                #pragma unroll
                for (int nt = 0; nt < 4; nt++)
                    acc[mt][nt] = __builtin_amdgcn_mfma_f32_16x16x32_bf16(
                        afrag[mt], bfrag[nt], acc[mt][nt], 0, 0, 0);
        }
        __syncthreads();
    }

    // ---- Epilogue. C/D layout: col = lane&15, row = quad*4 + reg. ----
    float bhv[4], wpr0[4], wpr1[4], wpr2[4], w20[4], w21[4], w22[4];
    #pragma unroll
    for (int nt = 0; nt < 4; nt++) {
        const int col = n0 + wn * 64 + nt * 16 + l16;
        bhv[nt] = bh[col];
        w20[nt] = Wf[512 + col];
        w21[nt] = Wf[1536 + col];
        w22[nt] = Wf[2560 + col];
        wpr0[nt] = Wf[col]        - w20[nt] * INV_NM1;
        wpr1[nt] = Wf[1024 + col] - w21[nt] * INV_NM1;
        wpr2[nt] = Wf[2048 + col] - w22[nt] * INV_NM1;
    }

    float* ps = pslice + (size_t)((r >> 3) * 2 + wn) * OUT_ELEMS;

    float q0 = 0.f, q1 = 0.f, q2 = 0.f;   // per-lane partials of sum_i d2
    #pragma unroll
    for (int mt = 0; mt < 4; mt++) {
        #pragma unroll
        for (int rg = 0; rg < 4; rg++) {
            float p0 = 0.f, p1 = 0.f, p2 = 0.f;
            #pragma unroll
            for (int nt = 0; nt < 4; nt++) {
                float v = acc[mt][nt][rg] + bhv[nt];
                v = v > 0.f ? v : 0.f;
                p0 += v * wpr0[nt];
                p1 += v * wpr1[nt];
                p2 += v * wpr2[nt];
                q0 += v * w20[nt];
                q1 += v * w21[nt];
                q2 += v * w22[nt];
            }
            // reduce the 16 lanes of this quad (one row, 64 cols)
            #pragma unroll
            for (int off = 1; off < 16; off <<= 1) {
                p0 += __shfl_xor(p0, off, 64);
                p1 += __shfl_xor(p1, off, 64);
                p2 += __shfl_xor(p2, off, 64);
            }
            if (l16 == 0) {
                const int row = m0 + wm * 64 + mt * 16 + quad * 4 + rg;
                ps[row * 3 + 0] = p0;
                ps[row * 3 + 1] = p1;
                ps[row * 3 + 2] = p2;
            }
        }
    }
    // block-level sum of d2 partials -> 3 atomicAdds per block
    #pragma unroll
    for (int off = 1; off < 64; off <<= 1) {
        q0 += __shfl_xor(q0, off, 64);
        q1 += __shfl_xor(q1, off, 64);
        q2 += __shfl_xor(q2, off, 64);
    }
    if (lane == 0) { gsh[wave][0] = q0; gsh[wave][1] = q1; gsh[wave][2] = q2; }
    __syncthreads();
    if (tid < 3) {
        float t = gsh[0][tid] + gsh[1][tid] + gsh[2][tid] + gsh[3][tid];
        atomicAdd(&gsum[tid], t);
    }
}

// ---------------------------------------------------------------------------
// finalize: out[idx] = relu( sum_s pslice[s][idx] + gsum[a]*INV + bf[a] )
// ---------------------------------------------------------------------------
__global__ __launch_bounds__(256) void finalize_kernel(
    const float* __restrict__ pslice,   // [8][M*3]
    const float* __restrict__ gsum,     // [3]
    const float* __restrict__ bfb,      // [3]
    float* __restrict__ out)            // [M*3]
{
    const int idx = blockIdx.x * 256 + threadIdx.x;
    float s = 0.f;
    #pragma unroll
    for (int sl = 0; sl < 8; sl++)
        s += pslice[(size_t)sl * OUT_ELEMS + idx];
    const int a = idx % 3;
    const float v = s + gsum[a] * INV_NM1 + bfb[a];
    out[idx] = v > 0.f ? v : 0.f;
}

extern "C" void kernel_launch(void* const* d_in, const int* in_sizes, int n_in,
                              void* d_out, int out_size, void* d_ws, size_t ws_size,
                              hipStream_t stream) {
    const float* X   = (const float*)d_in[0];
    const float* Wh  = (const float*)d_in[1];
    const float* bh  = (const float*)d_in[2];
    const float* Wf  = (const float*)d_in[3];
    const float* bfb = (const float*)d_in[4];
    for (int i = 0; i < n_in; i++) {
        const float* p = (const float*)d_in[i];
        switch (in_sizes[i]) {
            case M_DIM * K_DIM: X   = p; break;
            case N_DIM * K_DIM: Wh  = p; break;
            case N_DIM:         bh  = p; break;
            case 3 * 2 * N_DIM: Wf  = p; break;
            case 3:             bfb = p; break;
            default: break;
        }
    }
    float* out    = (float*)d_out;
    float* gsum   = (float*)d_ws;                          // 3 fp32 (2KB pad)
    float* pslice = (float*)((char*)d_ws + 2048);          // 8 * 196608 fp32

    hipMemsetAsync(gsum, 0, 2048, stream);                 // zero gsum only;
    // pslice needs no clearing: every element is written exactly once.

    gemm_fused_kernel<<<2048, 256, 0, stream>>>(X, Wh, bh, Wf, gsum, pslice);
    finalize_kernel<<<OUT_ELEMS / 256, 256, 0, stream>>>(pslice, gsum, bfb, out);
}

// Round 6
// 380.621 us; speedup vs baseline: 1.4387x; 1.3077x over previous
//
#include <hip/hip_runtime.h>
#include <hip/hip_bf16.h>

// DQNNetwork: M=65536, K=768, N=512 hidden, 3 actions. All I/O fp32.
//   h = relu(X @ Wh^T + bh)
//   d1[i,a] = dot(h[i], Wf[a,0:512]);  d2[i,a] = dot(h[i], Wf[a,512:1024])
//   out[i,a] = relu( d1 - d2/(M-1) + bf[a] + (sum_i d2[i,a])/(M-1) )
// R6: fp32->bf16 convert pass (streaming), then m97-style DMA-staged bf16 GEMM
// with fused head epilogue. R5's register-staging K-loop was latency-bound
// (VGPR 136 -> 3 waves/SIMD, 16 VMEM->cvt->LDS per thread per k0).

#define M_DIM 65536
#define K_DIM 768
#define N_DIM 512
#define INV_NM1 (1.0f / 65535.0f)
#define OUT_ELEMS (M_DIM * 3)

typedef __attribute__((ext_vector_type(8))) short shortx8;   // 8 bf16 (4 VGPRs)
typedef __attribute__((ext_vector_type(4))) float floatx4;   // MFMA C/D

__device__ __forceinline__ unsigned short f2b(float f) {
    unsigned u = __float_as_uint(f);
    unsigned r = (u + 0x7fffu + ((u >> 16) & 1u)) >> 16;   // RNE
    return (unsigned short)r;
}

#if defined(__has_builtin)
#  if __has_builtin(__builtin_amdgcn_cvt_pk_bf16_f32)
#    define HAVE_CVT_PK_BF16 1
#  endif
#endif

__device__ __forceinline__ unsigned pack2bf(float x, float y) {
#ifdef HAVE_CVT_PK_BF16
    typedef __attribute__((ext_vector_type(2))) __bf16 bf16x2_t;
    bf16x2_t t = __builtin_amdgcn_cvt_pk_bf16_f32(x, y);
    return __builtin_bit_cast(unsigned, t);
#else
    return (unsigned)f2b(x) | ((unsigned)f2b(y) << 16);
#endif
}

// async global->LDS DMA, 16B/lane; LDS side deposits at (uniform base)+lane*16.
__device__ __forceinline__ void async16(const unsigned short* g, unsigned short* l) {
    __builtin_amdgcn_global_load_lds(
        (const __attribute__((address_space(1))) void*)g,
        (__attribute__((address_space(3))) void*)l,
        16, 0, 0);
}

// ---------------------------------------------------------------------------
// Streaming fp32 -> bf16 convert. 8 elems/thread (32B read, 16B write).
// ---------------------------------------------------------------------------
__global__ __launch_bounds__(256) void cvt_bf16_kernel(
    const float* __restrict__ src, unsigned short* __restrict__ dst, int n8)
{
    const int idx = blockIdx.x * 256 + threadIdx.x;
    if (idx >= n8) return;
    const float4 a = *(const float4*)(src + (size_t)idx * 8);
    const float4 b = *(const float4*)(src + (size_t)idx * 8 + 4);
    uint4 o;
    o.x = pack2bf(a.x, a.y); o.y = pack2bf(a.z, a.w);
    o.z = pack2bf(b.x, b.y); o.w = pack2bf(b.z, b.w);
    *(uint4*)(dst + (size_t)idx * 8) = o;
}

// ---------------------------------------------------------------------------
// m97-style bf16 GEMM + fused head.
// 128x128 tile, 4 waves (2x2 of 64x64), BK=64, 16x16x32 bf16 MFMA.
// Staging: global_load_lds 16B. DMA deposit is linear (base+lane*16), so the
// bank swizzle is applied on the GLOBAL side: within an 8-row issue, lane L
// fetches global chunk (L&7)^(L>>3) of row r0+(L>>3). LDS (row, slot v) then
// holds global chunk v^(row&7); frag readers invert. b128 frag reads hit the
// 8-words/bank floor = conflict-free (R4/R5: SQ_LDS_BANK_CONFLICT == 0 with
// the same XOR family).
// Block swizzle: 4 n-slots of one m-tile get ids congruent mod 8 -> same XCD
// (R4/R5: FETCH 399 -> 128 MB). No min-wave bound (R4: forcing it spilled acc).
// ---------------------------------------------------------------------------
__global__ __launch_bounds__(256) void gemm_bf16_kernel(
    const unsigned short* __restrict__ Xb,    // [M,K] bf16
    const unsigned short* __restrict__ Whb,   // [N,K] bf16
    const float* __restrict__ bh,             // [N]
    const float* __restrict__ Wf,             // [3,1024]
    float* __restrict__ gsum,                 // [3], pre-zeroed
    float* __restrict__ pslice)               // [8][M*3], each elem written once
{
    __shared__ unsigned short As[128 * 64];  // 16 KB
    __shared__ unsigned short Bs[128 * 64];  // 16 KB  (total 32768 exactly)

    const int tid  = threadIdx.x;
    const int wave = tid >> 6;
    const int lane = tid & 63;
    const int l16  = lane & 15;
    const int quad = lane >> 4;
    const int wm   = wave >> 1;
    const int wn   = wave & 1;

    // XCD-aware swizzle: b = g*32 + slot*8 + xcd; m-tile = g*8+xcd, n = slot.
    const int b  = blockIdx.x;
    const int g  = b >> 5;
    const int r  = b & 31;
    const int m0 = (g * 8 + (r & 7)) * 128;
    const int n0 = (r >> 3) * 128;

    floatx4 acc[4][4];
    #pragma unroll
    for (int i = 0; i < 4; i++)
        #pragma unroll
        for (int j = 0; j < 4; j++) {
            floatx4 z = {0.f, 0.f, 0.f, 0.f};
            acc[i][j] = z;
        }

    // Per-lane DMA source offsets (row/chunk within an 8-row issue group).
    const int u   = lane >> 3;               // 0..7: row within issue
    const int chg = (lane & 7) ^ u;          // global-side swizzled chunk
    const int sw  = l16 & 7;                 // frag-read swizzle key

    for (int k0 = 0; k0 < K_DIM; k0 += 64) {
        // 16 issues per matrix (8 rows x 1KB each); wave w takes 4 of each.
        #pragma unroll
        for (int it = 0; it < 4; it++) {
            const int j   = wave * 4 + it;   // issue 0..15 (wave-uniform)
            const int r0  = j * 8;
            const int row = r0 + u;
            async16(Xb  + (size_t)(m0 + row) * K_DIM + k0 + chg * 8, As + r0 * 64);
            async16(Whb + (size_t)(n0 + row) * K_DIM + k0 + chg * 8, Bs + r0 * 64);
        }
        __syncthreads();   // compiler drains vmcnt before barrier

        #pragma unroll
        for (int kk = 0; kk < 64; kk += 32) {
            const int c  = (kk >> 3) + quad;         // logical 16B chunk
            const int co = ((c ^ sw) << 3);          // physical elem offset
            shortx8 afrag[4], bfrag[4];
            #pragma unroll
            for (int mt = 0; mt < 4; mt++)
                afrag[mt] = *(const shortx8*)(As + (wm * 64 + mt * 16 + l16) * 64 + co);
            #pragma unroll
            for (int nt = 0; nt < 4; nt++)
                bfrag[nt] = *(const shortx8*)(Bs + (wn * 64 + nt * 16 + l16) * 64 + co);
            #pragma unroll
            for (int mt = 0; mt < 4; mt++)
                #pragma unroll
                for (int nt = 0; nt < 4; nt++)
                    acc[mt][nt] = __builtin_amdgcn_mfma_f32_16x16x32_bf16(
                        afrag[mt], bfrag[nt], acc[mt][nt], 0, 0, 0);
        }
        __syncthreads();
    }

    // ---- Epilogue. C/D layout: col = lane&15, row = quad*4 + reg. ----
    float bhv[4], wpr0[4], wpr1[4], wpr2[4], w20[4], w21[4], w22[4];
    #pragma unroll
    for (int nt = 0; nt < 4; nt++) {
        const int col = n0 + wn * 64 + nt * 16 + l16;
        bhv[nt] = bh[col];
        w20[nt] = Wf[512 + col];
        w21[nt] = Wf[1536 + col];
        w22[nt] = Wf[2560 + col];
        wpr0[nt] = Wf[col]        - w20[nt] * INV_NM1;
        wpr1[nt] = Wf[1024 + col] - w21[nt] * INV_NM1;
        wpr2[nt] = Wf[2048 + col] - w22[nt] * INV_NM1;
    }

    float* ps = pslice + (size_t)((r >> 3) * 2 + wn) * OUT_ELEMS;

    float q0 = 0.f, q1 = 0.f, q2 = 0.f;   // partials of sum_i d2[i,a]
    #pragma unroll
    for (int mt = 0; mt < 4; mt++) {
        #pragma unroll
        for (int rg = 0; rg < 4; rg++) {
            float p0 = 0.f, p1 = 0.f, p2 = 0.f;
            #pragma unroll
            for (int nt = 0; nt < 4; nt++) {
                float v = acc[mt][nt][rg] + bhv[nt];
                v = v > 0.f ? v : 0.f;
                p0 += v * wpr0[nt];
                p1 += v * wpr1[nt];
                p2 += v * wpr2[nt];
                q0 += v * w20[nt];
                q1 += v * w21[nt];
                q2 += v * w22[nt];
            }
            #pragma unroll
            for (int off = 1; off < 16; off <<= 1) {
                p0 += __shfl_xor(p0, off, 64);
                p1 += __shfl_xor(p1, off, 64);
                p2 += __shfl_xor(p2, off, 64);
            }
            if (l16 == 0) {
                const int row = m0 + wm * 64 + mt * 16 + quad * 4 + rg;
                ps[row * 3 + 0] = p0;
                ps[row * 3 + 1] = p1;
                ps[row * 3 + 2] = p2;
            }
        }
    }
    // block reduce of q via As reuse (keeps LDS at exactly 32768)
    #pragma unroll
    for (int off = 1; off < 64; off <<= 1) {
        q0 += __shfl_xor(q0, off, 64);
        q1 += __shfl_xor(q1, off, 64);
        q2 += __shfl_xor(q2, off, 64);
    }
    float* red = (float*)As;
    if (lane == 0) { red[wave * 3 + 0] = q0; red[wave * 3 + 1] = q1; red[wave * 3 + 2] = q2; }
    __syncthreads();
    if (tid < 3)
        atomicAdd(&gsum[tid], red[tid] + red[3 + tid] + red[6 + tid] + red[9 + tid]);
}

// ---------------------------------------------------------------------------
// Fallback (R5 path): fused fp32 register-staging GEMM, used if ws too small.
// ---------------------------------------------------------------------------
__global__ __launch_bounds__(256) void gemm_fused_fp32_kernel(
    const float* __restrict__ X, const float* __restrict__ Wh,
    const float* __restrict__ bh, const float* __restrict__ Wf,
    float* __restrict__ gsum, float* __restrict__ pslice)
{
    __shared__ unsigned short As[128 * 64];
    __shared__ unsigned short Bs[128 * 64];

    const int tid  = threadIdx.x;
    const int wave = tid >> 6;
    const int lane = tid & 63;
    const int l16  = lane & 15;
    const int quad = lane >> 4;
    const int wm   = wave >> 1;
    const int wn   = wave & 1;

    const int b  = blockIdx.x;
    const int g  = b >> 5;
    const int r  = b & 31;
    const int m0 = (g * 8 + (r & 7)) * 128;
    const int n0 = (r >> 3) * 128;

    floatx4 acc[4][4];
    #pragma unroll
    for (int i = 0; i < 4; i++)
        #pragma unroll
        for (int j = 0; j < 4; j++) {
            floatx4 z = {0.f, 0.f, 0.f, 0.f};
            acc[i][j] = z;
        }

    const int swr = l16 & 7;

    for (int k0 = 0; k0 < K_DIM; k0 += 64) {
        #pragma unroll
        for (int p = 0; p < 8; p++) {
            const int c   = p * 256 + tid;
            const int row = c >> 4;
            const int q   = c & 15;
            const int f4  = q << 2;
            const int jch = q >> 1;
            const int off = row * 64 + ((jch ^ (row & 7)) << 3) + ((q & 1) << 2);
            const float4 av = *(const float4*)(X  + (size_t)(m0 + row) * K_DIM + k0 + f4);
            const float4 bv = *(const float4*)(Wh + (size_t)(n0 + row) * K_DIM + k0 + f4);
            uint2 a2, b2;
            a2.x = pack2bf(av.x, av.y); a2.y = pack2bf(av.z, av.w);
            b2.x = pack2bf(bv.x, bv.y); b2.y = pack2bf(bv.z, bv.w);
            *(uint2*)(As + off) = a2;
            *(uint2*)(Bs + off) = b2;
        }
        __syncthreads();

        #pragma unroll
        for (int kk = 0; kk < 64; kk += 32) {
            shortx8 afrag[4], bfrag[4];
            const int jq = (kk >> 3) + quad;
            const int co = ((jq ^ swr) << 3);
            #pragma unroll
            for (int mt = 0; mt < 4; mt++)
                afrag[mt] = *(const shortx8*)(As + (wm * 64 + mt * 16 + l16) * 64 + co);
            #pragma unroll
            for (int nt = 0; nt < 4; nt++)
                bfrag[nt] = *(const shortx8*)(Bs + (wn * 64 + nt * 16 + l16) * 64 + co);
            #pragma unroll
            for (int mt = 0; mt < 4; mt++)
                #pragma unroll
                for (int nt = 0; nt < 4; nt++)
                    acc[mt][nt] = __builtin_amdgcn_mfma_f32_16x16x32_bf16(
                        afrag[mt], bfrag[nt], acc[mt][nt], 0, 0, 0);
        }
        __syncthreads();
    }

    float bhv[4], wpr0[4], wpr1[4], wpr2[4], w20[4], w21[4], w22[4];
    #pragma unroll
    for (int nt = 0; nt < 4; nt++) {
        const int col = n0 + wn * 64 + nt * 16 + l16;
        bhv[nt] = bh[col];
        w20[nt] = Wf[512 + col];
        w21[nt] = Wf[1536 + col];
        w22[nt] = Wf[2560 + col];
        wpr0[nt] = Wf[col]        - w20[nt] * INV_NM1;
        wpr1[nt] = Wf[1024 + col] - w21[nt] * INV_NM1;
        wpr2[nt] = Wf[2048 + col] - w22[nt] * INV_NM1;
    }

    float* ps = pslice + (size_t)((r >> 3) * 2 + wn) * OUT_ELEMS;

    float q0 = 0.f, q1 = 0.f, q2 = 0.f;
    #pragma unroll
    for (int mt = 0; mt < 4; mt++) {
        #pragma unroll
        for (int rg = 0; rg < 4; rg++) {
            float p0 = 0.f, p1 = 0.f, p2 = 0.f;
            #pragma unroll
            for (int nt = 0; nt < 4; nt++) {
                float v = acc[mt][nt][rg] + bhv[nt];
                v = v > 0.f ? v : 0.f;
                p0 += v * wpr0[nt];
                p1 += v * wpr1[nt];
                p2 += v * wpr2[nt];
                q0 += v * w20[nt];
                q1 += v * w21[nt];
                q2 += v * w22[nt];
            }
            #pragma unroll
            for (int off = 1; off < 16; off <<= 1) {
                p0 += __shfl_xor(p0, off, 64);
                p1 += __shfl_xor(p1, off, 64);
                p2 += __shfl_xor(p2, off, 64);
            }
            if (l16 == 0) {
                const int row = m0 + wm * 64 + mt * 16 + quad * 4 + rg;
                ps[row * 3 + 0] = p0;
                ps[row * 3 + 1] = p1;
                ps[row * 3 + 2] = p2;
            }
        }
    }
    #pragma unroll
    for (int off = 1; off < 64; off <<= 1) {
        q0 += __shfl_xor(q0, off, 64);
        q1 += __shfl_xor(q1, off, 64);
        q2 += __shfl_xor(q2, off, 64);
    }
    float* red = (float*)As;
    if (lane == 0) { red[wave * 3 + 0] = q0; red[wave * 3 + 1] = q1; red[wave * 3 + 2] = q2; }
    __syncthreads();
    if (tid < 3)
        atomicAdd(&gsum[tid], red[tid] + red[3 + tid] + red[6 + tid] + red[9 + tid]);
}

// ---------------------------------------------------------------------------
// finalize: out[idx] = relu( sum_s pslice[s][idx] + gsum[a]*INV + bf[a] )
// ---------------------------------------------------------------------------
__global__ __launch_bounds__(256) void finalize_kernel(
    const float* __restrict__ pslice, const float* __restrict__ gsum,
    const float* __restrict__ bfb, float* __restrict__ out)
{
    const int idx = blockIdx.x * 256 + threadIdx.x;
    float s = 0.f;
    #pragma unroll
    for (int sl = 0; sl < 8; sl++)
        s += pslice[(size_t)sl * OUT_ELEMS + idx];
    const int a = idx % 3;
    const float v = s + gsum[a] * INV_NM1 + bfb[a];
    out[idx] = v > 0.f ? v : 0.f;
}

extern "C" void kernel_launch(void* const* d_in, const int* in_sizes, int n_in,
                              void* d_out, int out_size, void* d_ws, size_t ws_size,
                              hipStream_t stream) {
    const float* X   = (const float*)d_in[0];
    const float* Wh  = (const float*)d_in[1];
    const float* bh  = (const float*)d_in[2];
    const float* Wf  = (const float*)d_in[3];
    const float* bfb = (const float*)d_in[4];
    for (int i = 0; i < n_in; i++) {
        const float* p = (const float*)d_in[i];
        switch (in_sizes[i]) {
            case M_DIM * K_DIM: X   = p; break;
            case N_DIM * K_DIM: Wh  = p; break;
            case N_DIM:         bh  = p; break;
            case 3 * 2 * N_DIM: Wf  = p; break;
            case 3:             bfb = p; break;
            default: break;
        }
    }
    float* out = (float*)d_out;

    // ws layout: [gsum 2048][pslice 6.29MB][Xb 96MB][Whb 0.75MB]
    char* w = (char*)d_ws;
    float*          gsum   = (float*)w;
    float*          pslice = (float*)(w + 2048);
    unsigned short* Xb     = (unsigned short*)(w + 2048 + (size_t)8 * OUT_ELEMS * 4);
    unsigned short* Whb    = Xb + (size_t)M_DIM * K_DIM;
    const size_t need = 2048 + (size_t)8 * OUT_ELEMS * 4
                      + (size_t)(M_DIM + N_DIM) * K_DIM * 2;

    hipMemsetAsync(gsum, 0, 2048, stream);

    if (ws_size >= need) {
        cvt_bf16_kernel<<<(M_DIM * K_DIM / 8) / 256, 256, 0, stream>>>(X, Xb, M_DIM * K_DIM / 8);
        cvt_bf16_kernel<<<(N_DIM * K_DIM / 8) / 256, 256, 0, stream>>>(Wh, Whb, N_DIM * K_DIM / 8);
        gemm_bf16_kernel<<<2048, 256, 0, stream>>>(Xb, Whb, bh, Wf, gsum, pslice);
    } else {
        gemm_fused_fp32_kernel<<<2048, 256, 0, stream>>>(X, Wh, bh, Wf, gsum, pslice);
    }
    finalize_kernel<<<OUT_ELEMS / 256, 256, 0, stream>>>(pslice, gsum, bfb, out);
}

// Round 7
// 356.934 us; speedup vs baseline: 1.5342x; 1.0664x over previous
//
#include <hip/hip_runtime.h>
#include <hip/hip_bf16.h>

// DQNNetwork: M=65536, K=768, N=512 hidden, 3 actions. All I/O fp32.
//   h = relu(X @ Wh^T + bh)
//   d1[i,a] = dot(h[i], Wf[a,0:512]);  d2[i,a] = dot(h[i], Wf[a,512:1024])
//   out[i,a] = relu( d1 - d2/(M-1) + bf[a] + (sum_i d2[i,a])/(M-1) )
// R7: X staged fp32 via global_load_lds (no standalone X convert pass);
// fp32->bf16 conversion happens at fragment-read time (v_cvt_pk_bf16_f32).
// Wh pre-converted to bf16 by a tiny kernel (0.75 MB).

#define M_DIM 65536
#define K_DIM 768
#define N_DIM 512
#define INV_NM1 (1.0f / 65535.0f)
#define OUT_ELEMS (M_DIM * 3)

typedef __attribute__((ext_vector_type(8))) short shortx8;   // 8 bf16 (4 VGPRs)
typedef __attribute__((ext_vector_type(4))) float floatx4;   // MFMA C/D
typedef __attribute__((ext_vector_type(4))) unsigned int uintx4;

__device__ __forceinline__ unsigned short f2b(float f) {
    unsigned u = __float_as_uint(f);
    unsigned r = (u + 0x7fffu + ((u >> 16) & 1u)) >> 16;   // RNE
    return (unsigned short)r;
}

#if defined(__has_builtin)
#  if __has_builtin(__builtin_amdgcn_cvt_pk_bf16_f32)
#    define HAVE_CVT_PK_BF16 1
#  endif
#endif

__device__ __forceinline__ unsigned pack2bf(float x, float y) {   // {x->lo, y->hi}, HW-verified R6
#ifdef HAVE_CVT_PK_BF16
    typedef __attribute__((ext_vector_type(2))) __bf16 bf16x2_t;
    bf16x2_t t = __builtin_amdgcn_cvt_pk_bf16_f32(x, y);
    return __builtin_bit_cast(unsigned, t);
#else
    return (unsigned)f2b(x) | ((unsigned)f2b(y) << 16);
#endif
}

// async global->LDS DMA, 16B/lane; deposits at (wave-uniform base) + lane*16.
__device__ __forceinline__ void async16(const void* g, void* l) {
    __builtin_amdgcn_global_load_lds(
        (const __attribute__((address_space(1))) void*)g,
        (__attribute__((address_space(3))) void*)l,
        16, 0, 0);
}

// ---------------------------------------------------------------------------
// Streaming fp32 -> bf16 convert (used for Wh only, 0.75 MB).
// ---------------------------------------------------------------------------
__global__ __launch_bounds__(256) void cvt_bf16_kernel(
    const float* __restrict__ src, unsigned short* __restrict__ dst, int n8)
{
    const int idx = blockIdx.x * 256 + threadIdx.x;
    if (idx >= n8) return;
    const float4 a = *(const float4*)(src + (size_t)idx * 8);
    const float4 b = *(const float4*)(src + (size_t)idx * 8 + 4);
    uint4 o;
    o.x = pack2bf(a.x, a.y); o.y = pack2bf(a.z, a.w);
    o.z = pack2bf(b.x, b.y); o.w = pack2bf(b.z, b.w);
    *(uint4*)(dst + (size_t)idx * 8) = o;
}

// ---------------------------------------------------------------------------
// Fused GEMM + head. 128x128 tile, 4 waves (2x2 of 64x64), BK=64, 16x16x32.
// A (X) staged as FP32 via DMA: 32 KB, chunk c of row r stored at slot c^(r&15)
//   (each ds_read_b128 reads one 16B chunk, so the frag's two chunks are read
//   at independent swizzled slots -> 2 lanes/bank-group = conflict-free).
// B (Whb) staged bf16 via DMA, 16 KB, slot c^(r&7) (R6: zero conflicts).
// fp32->bf16 at frag-read: 2x ds_read_b128 + 4x v_cvt_pk_bf16_f32 per A-frag.
// Block swizzle: 4 n-slots of an m-tile -> same XCD (R4-R6: FETCH 399->128MB).
// No min-wave bound (R4: forcing it spilled acc).
// ---------------------------------------------------------------------------
__global__ __launch_bounds__(256) void gemm_fused_kernel(
    const float* __restrict__ X,              // [M,K] fp32
    const unsigned short* __restrict__ Whb,   // [N,K] bf16
    const float* __restrict__ bh,             // [N]
    const float* __restrict__ Wf,             // [3,1024]
    float* __restrict__ gsum,                 // [3], pre-zeroed
    float* __restrict__ pslice)               // [8][M*3], each elem written once
{
    __shared__ float          As[128 * 64];  // 32 KB fp32
    __shared__ unsigned short Bs[128 * 64];  // 16 KB bf16   (total 48 KB)

    const int tid  = threadIdx.x;
    const int wave = tid >> 6;
    const int lane = tid & 63;
    const int l16  = lane & 15;
    const int quad = lane >> 4;
    const int wm   = wave >> 1;
    const int wn   = wave & 1;

    // XCD-aware swizzle: b = g*32 + slot*8 + xcd; m-tile = g*8+xcd, n = slot.
    const int b  = blockIdx.x;
    const int g  = b >> 5;
    const int r  = b & 31;
    const int m0 = (g * 8 + (r & 7)) * 128;
    const int n0 = (r >> 3) * 128;

    floatx4 acc[4][4];
    #pragma unroll
    for (int i = 0; i < 4; i++)
        #pragma unroll
        for (int j = 0; j < 4; j++) {
            floatx4 z = {0.f, 0.f, 0.f, 0.f};
            acc[i][j] = z;
        }

    // DMA lane mapping. A: 1KB issue = 4 fp32 rows; B: 1KB = 8 bf16 rows.
    const int uA = lane >> 4, sAch = lane & 15;
    const int uB = lane >> 3, sBch = lane & 7;

    for (int k0 = 0; k0 < K_DIM; k0 += 64) {
        #pragma unroll
        for (int it = 0; it < 8; it++) {           // A: 32 issues, 8/wave
            const int j   = wave * 8 + it;         // wave-uniform
            const int r0  = j * 4;
            const int row = r0 + uA;
            const int gch = sAch ^ (row & 15);
            async16(X + (size_t)(m0 + row) * K_DIM + k0 + gch * 4, As + r0 * 64);
        }
        #pragma unroll
        for (int it = 0; it < 4; it++) {           // B: 16 issues, 4/wave
            const int j   = wave * 4 + it;
            const int r0  = j * 8;
            const int row = r0 + uB;
            const int gch = sBch ^ (row & 7);
            async16(Whb + (size_t)(n0 + row) * K_DIM + k0 + gch * 8, Bs + r0 * 64);
        }
        __syncthreads();   // compiler drains vmcnt before barrier

        #pragma unroll
        for (int kk = 0; kk < 64; kk += 32) {
            shortx8 afrag[4], bfrag[4];
            const int c0 = (kk + quad * 8) >> 2;   // fp32 chunk index (even)
            const int cb = (kk >> 3) + quad;       // bf16 chunk index
            #pragma unroll
            for (int mt = 0; mt < 4; mt++) {
                const int row = wm * 64 + mt * 16 + l16;
                const int rs  = row & 15;
                const floatx4 v0 = *(const floatx4*)(As + row * 64 + ((c0 ^ rs) << 2));
                const floatx4 v1 = *(const floatx4*)(As + row * 64 + (((c0 + 1) ^ rs) << 2));
                uintx4 u;
                u[0] = pack2bf(v0[0], v0[1]); u[1] = pack2bf(v0[2], v0[3]);
                u[2] = pack2bf(v1[0], v1[1]); u[3] = pack2bf(v1[2], v1[3]);
                afrag[mt] = __builtin_bit_cast(shortx8, u);
            }
            #pragma unroll
            for (int nt = 0; nt < 4; nt++) {
                const int row = wn * 64 + nt * 16 + l16;
                bfrag[nt] = *(const shortx8*)(Bs + row * 64 + ((cb ^ (row & 7)) << 3));
            }
            #pragma unroll
            for (int mt = 0; mt < 4; mt++)
                #pragma unroll
                for (int nt = 0; nt < 4; nt++)
                    acc[mt][nt] = __builtin_amdgcn_mfma_f32_16x16x32_bf16(
                        afrag[mt], bfrag[nt], acc[mt][nt], 0, 0, 0);
        }
        __syncthreads();
    }

    // ---- Epilogue. C/D layout: col = lane&15, row = quad*4 + reg. ----
    float bhv[4], wpr0[4], wpr1[4], wpr2[4], w20[4], w21[4], w22[4];
    #pragma unroll
    for (int nt = 0; nt < 4; nt++) {
        const int col = n0 + wn * 64 + nt * 16 + l16;
        bhv[nt] = bh[col];
        w20[nt] = Wf[512 + col];
        w21[nt] = Wf[1536 + col];
        w22[nt] = Wf[2560 + col];
        wpr0[nt] = Wf[col]        - w20[nt] * INV_NM1;
        wpr1[nt] = Wf[1024 + col] - w21[nt] * INV_NM1;
        wpr2[nt] = Wf[2048 + col] - w22[nt] * INV_NM1;
    }

    float* ps = pslice + (size_t)((r >> 3) * 2 + wn) * OUT_ELEMS;

    float q0 = 0.f, q1 = 0.f, q2 = 0.f;   // partials of sum_i d2[i,a]
    #pragma unroll
    for (int mt = 0; mt < 4; mt++) {
        #pragma unroll
        for (int rg = 0; rg < 4; rg++) {
            float p0 = 0.f, p1 = 0.f, p2 = 0.f;
            #pragma unroll
            for (int nt = 0; nt < 4; nt++) {
                float v = acc[mt][nt][rg] + bhv[nt];
                v = v > 0.f ? v : 0.f;
                p0 += v * wpr0[nt];
                p1 += v * wpr1[nt];
                p2 += v * wpr2[nt];
                q0 += v * w20[nt];
                q1 += v * w21[nt];
                q2 += v * w22[nt];
            }
            #pragma unroll
            for (int off = 1; off < 16; off <<= 1) {
                p0 += __shfl_xor(p0, off, 64);
                p1 += __shfl_xor(p1, off, 64);
                p2 += __shfl_xor(p2, off, 64);
            }
            if (l16 == 0) {
                const int row = m0 + wm * 64 + mt * 16 + quad * 4 + rg;
                ps[row * 3 + 0] = p0;
                ps[row * 3 + 1] = p1;
                ps[row * 3 + 2] = p2;
            }
        }
    }
    #pragma unroll
    for (int off = 1; off < 64; off <<= 1) {
        q0 += __shfl_xor(q0, off, 64);
        q1 += __shfl_xor(q1, off, 64);
        q2 += __shfl_xor(q2, off, 64);
    }
    float* red = (float*)As;   // reuse LDS for the 48B block reduction
    if (lane == 0) { red[wave * 3 + 0] = q0; red[wave * 3 + 1] = q1; red[wave * 3 + 2] = q2; }
    __syncthreads();
    if (tid < 3)
        atomicAdd(&gsum[tid], red[tid] + red[3 + tid] + red[6 + tid] + red[9 + tid]);
}

// ---------------------------------------------------------------------------
// finalize: out[idx] = relu( sum_s pslice[s][idx] + gsum[a]*INV + bf[a] )
// ---------------------------------------------------------------------------
__global__ __launch_bounds__(256) void finalize_kernel(
    const float* __restrict__ pslice, const float* __restrict__ gsum,
    const float* __restrict__ bfb, float* __restrict__ out)
{
    const int idx = blockIdx.x * 256 + threadIdx.x;
    float s = 0.f;
    #pragma unroll
    for (int sl = 0; sl < 8; sl++)
        s += pslice[(size_t)sl * OUT_ELEMS + idx];
    const int a = idx % 3;
    const float v = s + gsum[a] * INV_NM1 + bfb[a];
    out[idx] = v > 0.f ? v : 0.f;
}

// ---------------------------------------------------------------------------
// Fallback (R5 path, HW-verified): fused fp32 register-staging GEMM.
// ---------------------------------------------------------------------------
__global__ __launch_bounds__(256) void gemm_fused_fp32_kernel(
    const float* __restrict__ X, const float* __restrict__ Wh,
    const float* __restrict__ bh, const float* __restrict__ Wf,
    float* __restrict__ gsum, float* __restrict__ pslice)
{
    __shared__ unsigned short As[128 * 64];
    __shared__ unsigned short Bs[128 * 64];

    const int tid  = threadIdx.x;
    const int wave = tid >> 6;
    const int lane = tid & 63;
    const int l16  = lane & 15;
    const int quad = lane >> 4;
    const int wm   = wave >> 1;
    const int wn   = wave & 1;

    const int b  = blockIdx.x;
    const int g  = b >> 5;
    const int r  = b & 31;
    const int m0 = (g * 8 + (r & 7)) * 128;
    const int n0 = (r >> 3) * 128;

    floatx4 acc[4][4];
    #pragma unroll
    for (int i = 0; i < 4; i++)
        #pragma unroll
        for (int j = 0; j < 4; j++) {
            floatx4 z = {0.f, 0.f, 0.f, 0.f};
            acc[i][j] = z;
        }

    const int swr = l16 & 7;

    for (int k0 = 0; k0 < K_DIM; k0 += 64) {
        #pragma unroll
        for (int p = 0; p < 8; p++) {
            const int c   = p * 256 + tid;
            const int row = c >> 4;
            const int q   = c & 15;
            const int f4  = q << 2;
            const int jch = q >> 1;
            const int off = row * 64 + ((jch ^ (row & 7)) << 3) + ((q & 1) << 2);
            const float4 av = *(const float4*)(X  + (size_t)(m0 + row) * K_DIM + k0 + f4);
            const float4 bv = *(const float4*)(Wh + (size_t)(n0 + row) * K_DIM + k0 + f4);
            uint2 a2, b2;
            a2.x = pack2bf(av.x, av.y); a2.y = pack2bf(av.z, av.w);
            b2.x = pack2bf(bv.x, bv.y); b2.y = pack2bf(bv.z, bv.w);
            *(uint2*)(As + off) = a2;
            *(uint2*)(Bs + off) = b2;
        }
        __syncthreads();

        #pragma unroll
        for (int kk = 0; kk < 64; kk += 32) {
            shortx8 afrag[4], bfrag[4];
            const int jq = (kk >> 3) + quad;
            const int co = ((jq ^ swr) << 3);
            #pragma unroll
            for (int mt = 0; mt < 4; mt++)
                afrag[mt] = *(const shortx8*)(As + (wm * 64 + mt * 16 + l16) * 64 + co);
            #pragma unroll
            for (int nt = 0; nt < 4; nt++)
                bfrag[nt] = *(const shortx8*)(Bs + (wn * 64 + nt * 16 + l16) * 64 + co);
            #pragma unroll
            for (int mt = 0; mt < 4; mt++)
                #pragma unroll
                for (int nt = 0; nt < 4; nt++)
                    acc[mt][nt] = __builtin_amdgcn_mfma_f32_16x16x32_bf16(
                        afrag[mt], bfrag[nt], acc[mt][nt], 0, 0, 0);
        }
        __syncthreads();
    }

    float bhv[4], wpr0[4], wpr1[4], wpr2[4], w20[4], w21[4], w22[4];
    #pragma unroll
    for (int nt = 0; nt < 4; nt++) {
        const int col = n0 + wn * 64 + nt * 16 + l16;
        bhv[nt] = bh[col];
        w20[nt] = Wf[512 + col];
        w21[nt] = Wf[1536 + col];
        w22[nt] = Wf[2560 + col];
        wpr0[nt] = Wf[col]        - w20[nt] * INV_NM1;
        wpr1[nt] = Wf[1024 + col] - w21[nt] * INV_NM1;
        wpr2[nt] = Wf[2048 + col] - w22[nt] * INV_NM1;
    }

    float* ps = pslice + (size_t)((r >> 3) * 2 + wn) * OUT_ELEMS;

    float q0 = 0.f, q1 = 0.f, q2 = 0.f;
    #pragma unroll
    for (int mt = 0; mt < 4; mt++) {
        #pragma unroll
        for (int rg = 0; rg < 4; rg++) {
            float p0 = 0.f, p1 = 0.f, p2 = 0.f;
            #pragma unroll
            for (int nt = 0; nt < 4; nt++) {
                float v = acc[mt][nt][rg] + bhv[nt];
                v = v > 0.f ? v : 0.f;
                p0 += v * wpr0[nt];
                p1 += v * wpr1[nt];
                p2 += v * wpr2[nt];
                q0 += v * w20[nt];
                q1 += v * w21[nt];
                q2 += v * w22[nt];
            }
            #pragma unroll
            for (int off = 1; off < 16; off <<= 1) {
                p0 += __shfl_xor(p0, off, 64);
                p1 += __shfl_xor(p1, off, 64);
                p2 += __shfl_xor(p2, off, 64);
            }
            if (l16 == 0) {
                const int row = m0 + wm * 64 + mt * 16 + quad * 4 + rg;
                ps[row * 3 + 0] = p0;
                ps[row * 3 + 1] = p1;
                ps[row * 3 + 2] = p2;
            }
        }
    }
    #pragma unroll
    for (int off = 1; off < 64; off <<= 1) {
        q0 += __shfl_xor(q0, off, 64);
        q1 += __shfl_xor(q1, off, 64);
        q2 += __shfl_xor(q2, off, 64);
    }
    float* red = (float*)As;
    if (lane == 0) { red[wave * 3 + 0] = q0; red[wave * 3 + 1] = q1; red[wave * 3 + 2] = q2; }
    __syncthreads();
    if (tid < 3)
        atomicAdd(&gsum[tid], red[tid] + red[3 + tid] + red[6 + tid] + red[9 + tid]);
}

extern "C" void kernel_launch(void* const* d_in, const int* in_sizes, int n_in,
                              void* d_out, int out_size, void* d_ws, size_t ws_size,
                              hipStream_t stream) {
    const float* X   = (const float*)d_in[0];
    const float* Wh  = (const float*)d_in[1];
    const float* bh  = (const float*)d_in[2];
    const float* Wf  = (const float*)d_in[3];
    const float* bfb = (const float*)d_in[4];
    for (int i = 0; i < n_in; i++) {
        const float* p = (const float*)d_in[i];
        switch (in_sizes[i]) {
            case M_DIM * K_DIM: X   = p; break;
            case N_DIM * K_DIM: Wh  = p; break;
            case N_DIM:         bh  = p; break;
            case 3 * 2 * N_DIM: Wf  = p; break;
            case 3:             bfb = p; break;
            default: break;
        }
    }
    float* out = (float*)d_out;

    // ws layout: [gsum 2048][pslice 6.29MB][Whb 0.75MB]
    char* w = (char*)d_ws;
    float*          gsum   = (float*)w;
    float*          pslice = (float*)(w + 2048);
    unsigned short* Whb    = (unsigned short*)(w + 2048 + (size_t)8 * OUT_ELEMS * 4);
    const size_t need = 2048 + (size_t)8 * OUT_ELEMS * 4 + (size_t)N_DIM * K_DIM * 2;

    hipMemsetAsync(gsum, 0, 2048, stream);

    if (ws_size >= need) {
        cvt_bf16_kernel<<<(N_DIM * K_DIM / 8) / 256, 256, 0, stream>>>(Wh, Whb, N_DIM * K_DIM / 8);
        gemm_fused_kernel<<<2048, 256, 0, stream>>>(X, Whb, bh, Wf, gsum, pslice);
    } else {
        gemm_fused_fp32_kernel<<<2048, 256, 0, stream>>>(X, Wh, bh, Wf, gsum, pslice);
    }
    finalize_kernel<<<OUT_ELEMS / 256, 256, 0, stream>>>(pslice, gsum, bfb, out);
}